// Round 17
// baseline (277.517 us; speedup 1.0000x reference)
//
#include <hip/hip_runtime.h>
#include <hip/hip_fp16.h>
#include <math.h>

#define NSEG 126
#define PI_F 3.14159265358979323846f

typedef _Float16 f16x8 __attribute__((ext_vector_type(8)));
typedef float f32x4 __attribute__((ext_vector_type(4)));
#define MFMA(A,B,C) __builtin_amdgcn_mfma_f32_16x16x32_f16(A,B,C,0,0,0)

__device__ __forceinline__ unsigned bitrev8(unsigned v) { return __brev(v) >> 24; }
__device__ __forceinline__ float2 cmulc(float2 a, float2 b) {
    return make_float2(a.x*b.x - a.y*b.y, a.x*b.y + a.y*b.x);
}
__device__ __forceinline__ float2 mulmi(float2 a){ return make_float2(a.y, -a.x); }
__device__ __forceinline__ unsigned f2h2(float2 v) {
    return __builtin_bit_cast(unsigned, __float22half2_rn(v));
}
__device__ __forceinline__ f16x8 pack4u(unsigned a, unsigned b, unsigned c, unsigned d) {
    uint4 u = make_uint4(a, b, c, d);
    return __builtin_bit_cast(f16x8, u);
}

// ---------------------------------------------------------------------------
// Scalarized v2 shuffle-FFT for the ROW pass (unchanged from R16; proven).
// ---------------------------------------------------------------------------
#define BFLY(v, W) { float px_=__shfl_xor(v.x,HL), py_=__shfl_xor(v.y,HL); \
  if (up) { float dx_=px_-v.x, dy_=py_-v.y; v=make_float2(dx_*W.x-dy_*W.y, dx_*W.y+dy_*W.x); } \
  else    { v=make_float2(v.x+px_, v.y+py_); } }

#define ROW4(a,b,c,d) BFLY(a,w0) BFLY(b,w1) BFLY(c,w2) BFLY(d,w3)

#define FFT_STAGES(ALL) \
  { const int HL=32; const bool up=(lane&32)!=0; float s_,c_; \
    __sincosf(-PI_F*(float)(lane&31)*(1.0f/32.0f),&s_,&c_); \
    float2 w0=make_float2(c_,s_); \
    float2 w1=cmulc(w0,make_float2(0.99969882f,-0.02454123f)); \
    float2 w2=cmulc(w0,make_float2(0.99879546f,-0.04906767f)); \
    float2 w3=cmulc(w0,make_float2(0.99729046f,-0.07356456f)); ALL } \
  { const int HL=16; const bool up=(lane&16)!=0; float s_,c_; \
    __sincosf(-PI_F*(float)(lane&15)*(1.0f/16.0f),&s_,&c_); \
    float2 w0=make_float2(c_,s_); \
    float2 w1=cmulc(w0,make_float2(0.99879546f,-0.04906767f)); \
    float2 w2=cmulc(w0,make_float2(0.99518473f,-0.09801714f)); \
    float2 w3=cmulc(w0,make_float2(0.98917651f,-0.14673047f)); ALL } \
  { const int HL=8; const bool up=(lane&8)!=0; float s_,c_; \
    __sincosf(-PI_F*(float)(lane&7)*(1.0f/8.0f),&s_,&c_); \
    float2 w0=make_float2(c_,s_); \
    float2 w1=cmulc(w0,make_float2(0.99518473f,-0.09801714f)); \
    float2 w2=cmulc(w0,make_float2(0.98078528f,-0.19509032f)); \
    float2 w3=cmulc(w0,make_float2(0.95694034f,-0.29028468f)); ALL } \
  { const int HL=4; const bool up=(lane&4)!=0; float s_,c_; \
    __sincosf(-PI_F*(float)(lane&3)*(1.0f/4.0f),&s_,&c_); \
    float2 w0=make_float2(c_,s_); \
    float2 w1=cmulc(w0,make_float2(0.98078528f,-0.19509032f)); \
    float2 w2=cmulc(w0,make_float2(0.92387953f,-0.38268343f)); \
    float2 w3=cmulc(w0,make_float2(0.83146961f,-0.55557023f)); ALL } \
  { const int HL=2; const bool up=(lane&2)!=0; \
    float2 w0=(lane&1)?make_float2(0.f,-1.f):make_float2(1.f,0.f); \
    float2 w1=cmulc(w0,make_float2(0.92387953f,-0.38268343f)); \
    float2 w2=cmulc(w0,make_float2(0.70710678f,-0.70710678f)); \
    float2 w3=cmulc(w0,make_float2(0.38268343f,-0.92387953f)); ALL } \
  { const int HL=1; const bool up=(lane&1)!=0; \
    float2 w0=make_float2(1.f,0.f); \
    float2 w1=make_float2(0.70710678f,-0.70710678f); \
    float2 w2=make_float2(0.f,-1.f); \
    float2 w3=make_float2(-0.70710678f,-0.70710678f); ALL }

#define FIN(a0,a1,a2,a3) { float2 u_,v_; \
  u_=a0; v_=a2; a0=make_float2(u_.x+v_.x,u_.y+v_.y); a2=make_float2(u_.x-v_.x,u_.y-v_.y); \
  u_=a1; v_=a3; a1=make_float2(u_.x+v_.x,u_.y+v_.y); a3=mulmi(make_float2(u_.x-v_.x,u_.y-v_.y)); \
  u_=a0; v_=a1; a0=make_float2(u_.x+v_.x,u_.y+v_.y); a1=make_float2(u_.x-v_.x,u_.y-v_.y); \
  u_=a2; v_=a3; a2=make_float2(u_.x+v_.x,u_.y+v_.y); a3=make_float2(u_.x-v_.x,u_.y-v_.y); }

// ---------------------------------------------------------------------------
// Fused prep: bucket j = 255-c; pack r | mirror(r)<<8 | seg<<16 (natural r).
// ---------------------------------------------------------------------------
__global__ __launch_bounds__(1024) void prep_all(
    const int* __restrict__ rr, const int* __restrict__ cc,
    const int* __restrict__ seg, int n,
    int* __restrict__ starts, int* __restrict__ b_pack, float* __restrict__ acc)
{
    __shared__ int cnt[128];
    __shared__ int cur[128];
    int tid = threadIdx.x;
    if (tid < NSEG * 3) acc[tid] = 0.f;
    if (tid < 128) cnt[tid] = 0;
    __syncthreads();
    for (int i = tid; i < n; i += 1024) {
        int c = cc[i], r = rr[i];
        if ((c > 128) || (c == 128 && r > 128)) atomicAdd(&cnt[255 - c], 1);
    }
    __syncthreads();
    if (tid < 64) {
        int2 c2 = reinterpret_cast<const int2*>(cnt)[tid];
        int lsum = c2.x + c2.y;
        int pre = lsum;
        #pragma unroll
        for (int off = 1; off < 64; off <<= 1) {
            int v = __shfl_up(pre, off);
            if (tid >= off) pre += v;
        }
        int excl = pre - lsum;
        int2 outv = make_int2(excl, excl + c2.x);
        reinterpret_cast<int2*>(cur)[tid] = outv;
        reinterpret_cast<int2*>(starts)[tid] = outv;
        if (tid == 63) starts[128] = excl + c2.x + c2.y;
    }
    __syncthreads();
    for (int i = tid; i < n; i += 1024) {
        int c = cc[i], r = rr[i];
        if ((c > 128) || (c == 128 && r > 128)) {
            int j = 255 - c;
            int pos = atomicAdd(&cur[j], 1);
            b_pack[pos] = r | (((256 - r) & 255) << 8) | (seg[i] << 16);
        }
    }
}

// ---------------------------------------------------------------------------
// One-time W fragment tables: A-frag layout m = lane&15, k = ks*32+(lane>>4)*8+j.
// AWr[tile=mt*8+ks][lane] = uint4 of 8 f16: cos;  AWi: -sin.
// ---------------------------------------------------------------------------
__global__ __launch_bounds__(512) void prep_w(uint4* __restrict__ AWr,
                                              uint4* __restrict__ AWi)
{
    int gid  = blockIdx.x * 512 + threadIdx.x;    // grid 16 -> 8192
    int l    = gid & 63;
    int tile = gid >> 6;                          // 0..127 = mt*8+ks
    int mt = tile >> 3, ks = tile & 7;
    int u  = mt * 16 + (l & 15);
    int kb = ks * 32 + ((l >> 4) << 3);
    unsigned wr[8], wi[8];
    #pragma unroll
    for (int j = 0; j < 8; j++) {
        int t8 = (u * (kb + j)) & 255;
        float ang = (float)t8 * (2.0f * PI_F / 256.0f);
        float cs, sn;
        __sincosf(ang, &sn, &cs);
        wr[j] = (unsigned)__builtin_bit_cast(unsigned short, (_Float16)cs);
        wi[j] = (unsigned)__builtin_bit_cast(unsigned short, (_Float16)(-sn));
    }
    AWr[gid] = make_uint4(wr[0]|(wr[1]<<16), wr[2]|(wr[3]<<16),
                          wr[4]|(wr[5]<<16), wr[6]|(wr[7]<<16));
    AWi[gid] = make_uint4(wi[0]|(wi[1]<<16), wi[2]|(wi[3]<<16),
                          wi[4]|(wi[5]<<16), wi[6]|(wi[7]<<16));
}

// ---------------------------------------------------------------------------
// Row-pass (R16, unchanged): fp16 Gt; physical row q holds spectrum[bitrev8(q)].
// ---------------------------------------------------------------------------
#define ALL4 ROW4(x00,x01,x02,x03) ROW4(x10,x11,x12,x13) \
             ROW4(x20,x21,x22,x23) ROW4(x30,x31,x32,x33)

__global__ __launch_bounds__(512, 1) void rowfft_kernel(
    const float* __restrict__ inp, const float* __restrict__ tgt,
    unsigned* __restrict__ G, int pair_base)
{
    __shared__ unsigned T[256 * 17];
    int tid    = threadIdx.x;
    int wv     = tid >> 6;
    int lane   = tid & 63;
    int plocal = blockIdx.x >> 3;
    int rowgrp = blockIdx.x & 7;
    int row0   = (rowgrp << 5) + (wv << 2);
    size_t base = (((size_t)(pair_base + plocal)) << 16) + ((size_t)row0 << 8);
    const float4* s1 = (const float4*)(inp + base);
    const float4* s2 = (const float4*)(tgt + base);

    float4 A0 = s1[lane],       B0 = s2[lane];
    float4 A1 = s1[64 + lane],  B1 = s2[64 + lane];
    float4 A2 = s1[128 + lane], B2 = s2[128 + lane];
    float4 A3 = s1[192 + lane], B3 = s2[192 + lane];

    float2 x00 = make_float2(A0.x, B0.x), x01 = make_float2(A0.y, B0.y),
           x02 = make_float2(A0.z, B0.z), x03 = make_float2(A0.w, B0.w);
    float2 x10 = make_float2(A1.x, B1.x), x11 = make_float2(A1.y, B1.y),
           x12 = make_float2(A1.z, B1.z), x13 = make_float2(A1.w, B1.w);
    float2 x20 = make_float2(A2.x, B2.x), x21 = make_float2(A2.y, B2.y),
           x22 = make_float2(A2.z, B2.z), x23 = make_float2(A2.w, B2.w);
    float2 x30 = make_float2(A3.x, B3.x), x31 = make_float2(A3.y, B3.y),
           x32 = make_float2(A3.z, B3.z), x33 = make_float2(A3.w, B3.w);

    FFT_STAGES(ALL4)
    FIN(x00,x01,x02,x03) FIN(x10,x11,x12,x13)
    FIN(x20,x21,x22,x23) FIN(x30,x31,x32,x33)

    unsigned* dst = G + (((size_t)plocal) << 16) + (rowgrp << 5);
    #pragma unroll
    for (int pass = 0; pass < 2; pass++) {
        if ((wv >> 2) == pass) {
            int xr = ((wv & 3) << 2);
            unsigned* Tp = &T[(4 * lane) * 17 + xr];
            Tp[0]  = f2h2(x00); Tp[17] = f2h2(x01); Tp[34] = f2h2(x02); Tp[51] = f2h2(x03);
            Tp[1]  = f2h2(x10); Tp[18] = f2h2(x11); Tp[35] = f2h2(x12); Tp[52] = f2h2(x13);
            Tp[2]  = f2h2(x20); Tp[19] = f2h2(x21); Tp[36] = f2h2(x22); Tp[53] = f2h2(x23);
            Tp[3]  = f2h2(x30); Tp[20] = f2h2(x31); Tp[37] = f2h2(x32); Tp[54] = f2h2(x33);
        }
        __syncthreads();
        int xl = tid & 15;
        int qq = tid >> 4;
        #pragma unroll
        for (int ii = 0; ii < 8; ii++) {
            int q = qq + (ii << 5);
            dst[q * 256 + (pass << 4) + xl] = T[q * 17 + xl];
        }
        __syncthreads();
    }
}

// ---------------------------------------------------------------------------
// Column pass via MFMA: block = one pair; 8 panels x (2 strips of 16 cols).
// F = W x Ghat (complex via 4 real mfma chains), strips to LDS, then gather.
// ---------------------------------------------------------------------------
__global__ __launch_bounds__(512, 1) void colfft_mfma_kernel(
    const unsigned* __restrict__ G, const uint4* __restrict__ AWr,
    const uint4* __restrict__ AWi, const int* __restrict__ starts,
    const int* __restrict__ b_pack, float* __restrict__ acc)
{
    __shared__ float2 sL[16 * 257];              // 32,896 B
    __shared__ float2 sH[16 * 257];              // 32,896 B
    __shared__ float accl[NSEG * 3];
    int tid  = threadIdx.x;
    int wv   = tid >> 6;
    int lane = tid & 63;
    int l15  = lane & 15;
    int g8   = (lane >> 4) << 3;                 // k-subgroup offset
    const unsigned* Gp = G + (((size_t)blockIdx.x) << 16);

    for (int i = tid; i < NSEG * 3; i += 512) accl[i] = 0.f;

    int mt0 = wv << 1, mt1 = mt0 + 1;

    for (int p = 0; p < 8; p++) {
        __syncthreads();                          // strips free / accl ready
        int cbL = 16 * p + 1;
        int cbH = 240 - 16 * p;
        const unsigned* rowL = Gp + (size_t)bitrev8((unsigned)(cbL + l15)) * 256;
        const unsigned* rowH = Gp + (size_t)bitrev8((unsigned)(cbH + l15)) * 256;

        f32x4 aR0L = {0,0,0,0}, aI0L = {0,0,0,0}, aR0H = {0,0,0,0}, aI0H = {0,0,0,0};
        f32x4 aR1L = {0,0,0,0}, aI1L = {0,0,0,0}, aR1H = {0,0,0,0}, aI1H = {0,0,0,0};

        #pragma unroll
        for (int ks = 0; ks < 8; ks++) {
            int koff = ks * 32 + g8;
            uint4 bL0 = *(const uint4*)(rowL + koff);
            uint4 bL1 = *(const uint4*)(rowL + koff + 4);
            uint4 bH0 = *(const uint4*)(rowH + koff);
            uint4 bH1 = *(const uint4*)(rowH + koff + 4);
            uint4 wr0 = AWr[((mt0 << 3) + ks) * 64 + lane];
            uint4 wi0 = AWi[((mt0 << 3) + ks) * 64 + lane];
            uint4 wr1 = AWr[((mt1 << 3) + ks) * 64 + lane];
            uint4 wi1 = AWi[((mt1 << 3) + ks) * 64 + lane];

            f16x8 GrL = pack4u((bL0.x & 0xffffu) | (bL0.y << 16),
                               (bL0.z & 0xffffu) | (bL0.w << 16),
                               (bL1.x & 0xffffu) | (bL1.y << 16),
                               (bL1.z & 0xffffu) | (bL1.w << 16));
            unsigned giL0 = (bL0.x >> 16) | (bL0.y & 0xffff0000u);
            unsigned giL1 = (bL0.z >> 16) | (bL0.w & 0xffff0000u);
            unsigned giL2 = (bL1.x >> 16) | (bL1.y & 0xffff0000u);
            unsigned giL3 = (bL1.z >> 16) | (bL1.w & 0xffff0000u);
            f16x8 GiL  = pack4u(giL0, giL1, giL2, giL3);
            f16x8 nGiL = pack4u(giL0 ^ 0x80008000u, giL1 ^ 0x80008000u,
                                giL2 ^ 0x80008000u, giL3 ^ 0x80008000u);
            f16x8 GrH = pack4u((bH0.x & 0xffffu) | (bH0.y << 16),
                               (bH0.z & 0xffffu) | (bH0.w << 16),
                               (bH1.x & 0xffffu) | (bH1.y << 16),
                               (bH1.z & 0xffffu) | (bH1.w << 16));
            unsigned giH0 = (bH0.x >> 16) | (bH0.y & 0xffff0000u);
            unsigned giH1 = (bH0.z >> 16) | (bH0.w & 0xffff0000u);
            unsigned giH2 = (bH1.x >> 16) | (bH1.y & 0xffff0000u);
            unsigned giH3 = (bH1.z >> 16) | (bH1.w & 0xffff0000u);
            f16x8 GiH  = pack4u(giH0, giH1, giH2, giH3);
            f16x8 nGiH = pack4u(giH0 ^ 0x80008000u, giH1 ^ 0x80008000u,
                                giH2 ^ 0x80008000u, giH3 ^ 0x80008000u);

            f16x8 Wr0 = __builtin_bit_cast(f16x8, wr0);
            f16x8 Wi0 = __builtin_bit_cast(f16x8, wi0);
            f16x8 Wr1 = __builtin_bit_cast(f16x8, wr1);
            f16x8 Wi1 = __builtin_bit_cast(f16x8, wi1);

            aR0L = MFMA(Wr0, GrL, aR0L);  aR0L = MFMA(Wi0, nGiL, aR0L);
            aI0L = MFMA(Wr0, GiL, aI0L);  aI0L = MFMA(Wi0, GrL,  aI0L);
            aR0H = MFMA(Wr0, GrH, aR0H);  aR0H = MFMA(Wi0, nGiH, aR0H);
            aI0H = MFMA(Wr0, GiH, aI0H);  aI0H = MFMA(Wi0, GrH,  aI0H);
            aR1L = MFMA(Wr1, GrL, aR1L);  aR1L = MFMA(Wi1, nGiL, aR1L);
            aI1L = MFMA(Wr1, GiL, aI1L);  aI1L = MFMA(Wi1, GrL,  aI1L);
            aR1H = MFMA(Wr1, GrH, aR1H);  aR1H = MFMA(Wi1, nGiH, aR1H);
            aI1H = MFMA(Wr1, GiH, aI1H);  aI1H = MFMA(Wi1, GrH,  aI1H);
        }

        // C/D layout (m89-verified): elem i of lane -> row=(lane>>4)*4+i, col=lane&15
        {
            int cw  = l15 * 257;
            int rb0 = mt0 * 16 + ((lane >> 4) << 2);
            int rb1 = mt1 * 16 + ((lane >> 4) << 2);
            sL[cw + rb0 + 0] = make_float2(aR0L.x, aI0L.x);
            sL[cw + rb0 + 1] = make_float2(aR0L.y, aI0L.y);
            sL[cw + rb0 + 2] = make_float2(aR0L.z, aI0L.z);
            sL[cw + rb0 + 3] = make_float2(aR0L.w, aI0L.w);
            sH[cw + rb0 + 0] = make_float2(aR0H.x, aI0H.x);
            sH[cw + rb0 + 1] = make_float2(aR0H.y, aI0H.y);
            sH[cw + rb0 + 2] = make_float2(aR0H.z, aI0H.z);
            sH[cw + rb0 + 3] = make_float2(aR0H.w, aI0H.w);
            sL[cw + rb1 + 0] = make_float2(aR1L.x, aI1L.x);
            sL[cw + rb1 + 1] = make_float2(aR1L.y, aI1L.y);
            sL[cw + rb1 + 2] = make_float2(aR1L.z, aI1L.z);
            sL[cw + rb1 + 3] = make_float2(aR1L.w, aI1L.w);
            sH[cw + rb1 + 0] = make_float2(aR1H.x, aI1H.x);
            sH[cw + rb1 + 1] = make_float2(aR1H.y, aI1H.y);
            sH[cw + rb1 + 2] = make_float2(aR1H.z, aI1H.z);
            sH[cw + rb1 + 3] = make_float2(aR1H.w, aI1H.w);
        }
        __syncthreads();

        // gather: wave wv handles buckets jj = 2wv, 2wv+1 of this panel
        #pragma unroll
        for (int t = 0; t < 2; t++) {
            int jj = (wv << 1) + t;
            int j_ = (p << 4) + jj;
            const float2* Fhi = sH + (15 - jj) * 257;
            const float2* Flo = sL + jj * 257;
            int s0 = starts[j_], s1 = starts[j_ + 1];
            int e  = s0 + lane;
            int pk = (e < s1) ? b_pack[e] : 0;
            while (e < s1) {
                int e2  = e + 64;
                int pk2 = (e2 < s1) ? b_pack[e2] : 0;
                float2 a = Fhi[pk & 255];             // Fp(r, c_hi)
                float2 m = Flo[(pk >> 8) & 255];      // Fp(-r, -c_hi)
                int sg = pk >> 16;
                float f1x = a.x + m.x, f1y = a.y - m.y;   // 2*F1
                float dx  = a.x - m.x, dy  = a.y + m.y;   // 2i*F2
                atomicAdd(&accl[sg * 3 + 0], f1x * dy - f1y * dx);
                atomicAdd(&accl[sg * 3 + 1], f1x * f1x + f1y * f1y);
                atomicAdd(&accl[sg * 3 + 2], dx * dx + dy * dy);
                e = e2; pk = pk2;
            }
        }
    }
    __syncthreads();

    for (int i = tid; i < NSEG * 3; i += 512) {
        float v = accl[i];
        if (v != 0.f) atomicAdd(&acc[i], v);
    }
}

// ---------------------------------------------------------------------------
__global__ void final_kernel(const float* __restrict__ acc, const float* __restrict__ w,
                             float* __restrict__ out, float scale) {
    int lane = threadIdx.x;
    float val = 0.f;
    for (int s = lane; s < NSEG; s += 64) {
        float cr = acc[s * 3 + 0];
        float p1 = acc[s * 3 + 1];
        float p2 = acc[s * 3 + 2];
        float den = p1 * p2;
        float curve = den > 0.f ? fabsf(cr) * rsqrtf(den) : 0.f;
        val += curve * w[s + 1];
    }
    if (lane == 0) val += w[0];
    #pragma unroll
    for (int off = 32; off > 0; off >>= 1) val += __shfl_down(val, off);
    if (lane == 0) out[0] = scale * val;
}

// ---------------------------------------------------------------------------
extern "C" void kernel_launch(void* const* d_in, const int* in_sizes, int n_in,
                              void* d_out, int out_size, void* d_ws, size_t ws_size,
                              hipStream_t stream)
{
    const float* inp = (const float*)d_in[0];
    const float* tgt = (const float*)d_in[1];
    const float* wts = (const float*)d_in[2];
    const int*   rr  = (const int*)d_in[3];
    const int*   cc  = (const int*)d_in[4];
    const int*   sg  = (const int*)d_in[5];
    int npts   = in_sizes[3];
    int npairs = in_sizes[0] >> 16;               // B*C (65536 px/img)

    char* ws = (char*)d_ws;
    float* acc    = (float*)(ws + 0);             // 378 floats
    int*   starts = (int*)(ws + 2048);            // 129 ints
    int*   b_pack = (int*)(ws + 4096);
    size_t awoff = 4096 + (size_t)npts * 4;
    awoff = (awoff + 255) & ~(size_t)255;
    uint4* AWr = (uint4*)(ws + awoff);            // 128 KiB
    uint4* AWi = (uint4*)(ws + awoff + 131072);   // 128 KiB
    size_t goff = awoff + 262144;
    unsigned* G = (unsigned*)(ws + goff);

    size_t per_pair = (size_t)256 * 256 * 4;      // 256 KiB fp16 spectrum
    int maxchunk = (int)((ws_size > goff ? (ws_size - goff) : 0) / per_pair);
    if (maxchunk < 1) maxchunk = 1;
    if (maxchunk > npairs) maxchunk = npairs;

    prep_all<<<1, 1024, 0, stream>>>(rr, cc, sg, npts, starts, b_pack, acc);
    prep_w<<<16, 512, 0, stream>>>(AWr, AWi);

    for (int pb = 0; pb < npairs; pb += maxchunk) {
        int cp = npairs - pb < maxchunk ? npairs - pb : maxchunk;
        rowfft_kernel<<<cp * 8, 512, 0, stream>>>(inp, tgt, G, pb);
        colfft_mfma_kernel<<<cp, 512, 0, stream>>>(G, AWr, AWi, starts, b_pack, acc);
    }

    final_kernel<<<1, 64, 0, stream>>>(acc, wts, (float*)d_out, (float)npairs);
}